// Round 6
// baseline (128.039 us; speedup 1.0000x reference)
//
#include <hip/hip_runtime.h>
#include <hip/hip_bf16.h>

typedef __attribute__((ext_vector_type(4))) int   i32x4;
typedef __attribute__((ext_vector_type(8))) int   i32x8;
typedef __attribute__((ext_vector_type(16))) float f32x16;

#define D 1024
#define NROWS 4096          // B
#define SCALE_U 14.426950408889634f   // (1/T) * log2(e)
#define LN2 0.69314718055994530942f
#define LSE_SHIFT 16.0f     // |u| <= 14.43 => exp2(u-16) in [2^-30.5, 2^-1.5]: no max needed
#define NCC 32              // column chunks — one 128-col block each
#define BM 128              // block tile rows/cols
#define BKB 128             // K bytes (fp8 elems) per slab
#define NSLAB 8             // D / BKB

// ---------------- workspace layout ----------------
// zn      : 8192*1024 fp8 e4m3 (z1 rows pre-scaled by SCALE_U) @ 0        (8 MiB)
// psum    : 4096*32 f32                                        @ 8388608  (512 KiB)
// diag    : 4096 f32                                           @ 8912896  (16 KiB)
// contrib : 4096 f32                                           @ 8929280  (16 KiB)

__device__ __forceinline__ void gload16(const void* g, void* l) {
    __builtin_amdgcn_global_load_lds((const __attribute__((address_space(1))) void*)g,
                                     (__attribute__((address_space(3))) void*)l, 16, 0, 0);
}

// ---------- 1. row normalize + fp8 e4m3 cast (z1 rows pre-scaled) ----------
__global__ __launch_bounds__(256) void nrm_kernel(const float* __restrict__ feat,
                                                  unsigned char* __restrict__ zn) {
    const int row = blockIdx.x;           // 0..8191
    const int tid = threadIdx.x;          // 256, 4 floats each
    const float4 v = reinterpret_cast<const float4*>(feat + (size_t)row * D)[tid];
    float ss = v.x * v.x + v.y * v.y + v.z * v.z + v.w * v.w;
#pragma unroll
    for (int off = 32; off > 0; off >>= 1) ss += __shfl_down(ss, off);
    __shared__ float red[4];
    const int lane = tid & 63, wid = tid >> 6;
    if (lane == 0) red[wid] = ss;
    __syncthreads();
    const float tot = red[0] + red[1] + red[2] + red[3];
    const float nrm = fmaxf(sqrtf(tot), 1e-8f);
    const float sc = ((row < NROWS) ? SCALE_U : 1.0f) / nrm;
    int p = __builtin_amdgcn_cvt_pk_fp8_f32(v.x * sc, v.y * sc, 0, false);
    p     = __builtin_amdgcn_cvt_pk_fp8_f32(v.z * sc, v.w * sc, p, true);
    reinterpret_cast<int*>(zn)[(size_t)row * (D / 4) + tid] = p;
}

// ---------- 2. Gram (u = logits*log2e), MX-fp8 32x32x64, + fused LSE sums ----------
// R2/R5-proven 2-phase structure: 128x128 tile, 4 waves (2x2), wave tile 64x64,
// global_load_lds width=16 (linear dest, pre-swizzled source, swizzled ds_read),
// 4 blocks/CU, XCD-aware block swizzle. fp8 halves staging+LDS bytes; MFMA is
// mfma_scale_f32_32x32x64_f8f6f4 with uniform E8M0 scale = 127 (1.0) -> 2x rate.
// LDS rows are 128 B (BKB fp8), 8 x 16B chunks, swizzle phys = chunk ^ (row&7):
// ds_read_b128 pairs land 8 lanes per 16B bank-slot = conflict-free.
__global__ __launch_bounds__(256, 4) void gram_lse_kernel(const unsigned char* __restrict__ zn,
                                                          float* __restrict__ psum,
                                                          float* __restrict__ diag) {
    __shared__ __align__(16) unsigned char As[BM * BKB];   // 16 KiB
    __shared__ __align__(16) unsigned char Bs[BM * BKB];   // 16 KiB
    __shared__ float sbuf[BM][2];

    // XCD-aware swizzle: each XCD covers a 16-rowtile x 8-coltile region
    const int bid = blockIdx.x;            // 0..1023
    const int xcd = bid & 7, t = bid >> 3; // t: 0..127 within XCD
    const int rt = (xcd >> 2) * 16 + (t >> 3);   // 0..31
    const int cc = (xcd & 3) * 8 + (t & 7);      // 0..31

    const int tid = threadIdx.x;
    const int lane = tid & 63;
    const int wid  = tid >> 6;        // 0..3
    const int wm = wid >> 1, wn = wid & 1;
    const int l31 = lane & 31, h = lane >> 5;

    const unsigned char* z1 = zn;
    const unsigned char* z2 = zn + (size_t)NROWS * D;

    // staging: 8 lanes per 128B row; source chunk pre-swizzled so
    // LDS[row][p] = global[row][p ^ (row&7)]
    const int lrow8 = lane >> 3;                       // 0..7 == row&7
    const int cs    = (lane & 7) ^ lrow8;
    const unsigned char* gA = z1 + (size_t)(rt * BM + lrow8) * D + cs * 16;
    const unsigned char* gB = z2 + (size_t)(cc * BM + lrow8) * D + cs * 16;

    f32x16 acc[2][2];
#pragma unroll
    for (int i = 0; i < 2; i++)
#pragma unroll
        for (int j = 0; j < 2; j++)
#pragma unroll
            for (int r = 0; r < 16; r++) acc[i][j][r] = 0.f;

    for (int kb = 0; kb < NSLAB; ++kb) {
        __syncthreads();   // previous-iter readers done before overwrite
#pragma unroll
        for (int it = 0; it < 4; ++it) {
            const int r0 = (wid * 4 + it) * 8;         // wave-uniform row base
            gload16(gA + (size_t)r0 * D + kb * BKB, &As[r0 * BKB]);
            gload16(gB + (size_t)r0 * D + kb * BKB, &Bs[r0 * BKB]);
        }
        __syncthreads();   // vmcnt(0) drain: LDS tiles ready
#pragma unroll
        for (int kk = 0; kk < 2; ++kk) {
            i32x8 a[2], b[2];
            const int ch = kk * 4 + h * 2;
#pragma unroll
            for (int mf = 0; mf < 2; ++mf) {
                const int row = wm * 64 + mf * 32 + l31;
                const int x = row & 7;
                const i32x4 lo = *reinterpret_cast<const i32x4*>(&As[row * BKB + ((ch    ) ^ x) * 16]);
                const i32x4 hi = *reinterpret_cast<const i32x4*>(&As[row * BKB + ((ch + 1) ^ x) * 16]);
                a[mf] = __builtin_shufflevector(lo, hi, 0, 1, 2, 3, 4, 5, 6, 7);
            }
#pragma unroll
            for (int nf = 0; nf < 2; ++nf) {
                const int row = wn * 64 + nf * 32 + l31;
                const int x = row & 7;
                const i32x4 lo = *reinterpret_cast<const i32x4*>(&Bs[row * BKB + ((ch    ) ^ x) * 16]);
                const i32x4 hi = *reinterpret_cast<const i32x4*>(&Bs[row * BKB + ((ch + 1) ^ x) * 16]);
                b[nf] = __builtin_shufflevector(lo, hi, 0, 1, 2, 3, 4, 5, 6, 7);
            }
#pragma unroll
            for (int mf = 0; mf < 2; ++mf)
#pragma unroll
                for (int nf = 0; nf < 2; ++nf)
                    acc[mf][nf] = __builtin_amdgcn_mfma_scale_f32_32x32x64_f8f6f4(
                        a[mf], b[nf], acc[mf][nf], 0, 0,
                        0, 0x7f7f7f7f, 0, 0x7f7f7f7f);
        }
    }

    // ---- diagonal extraction (u_ii) on the 32 rt==cc blocks ----
    // 32x32 C/D layout: col = lane&31, row = (r&3) + 8*(r>>2) + 4*(lane>>5)
    if (rt == cc) {
#pragma unroll
        for (int mf = 0; mf < 2; ++mf)
#pragma unroll
            for (int nf = 0; nf < 2; ++nf)
#pragma unroll
                for (int r = 0; r < 16; ++r) {
                    const int rl = wm * 64 + mf * 32 + (r & 3) + 8 * (r >> 2) + 4 * h;
                    const int cl = wn * 64 + nf * 32 + l31;
                    if (rl == cl) diag[rt * BM + rl] = acc[mf][nf][r];
                }
    }

    // ---- fused LSE partial sums (fixed shift, no max): s = sum exp2(u - 16) ----
    // For each reg r: 32 cols live in the 32 lanes of this half -> butterfly-sum.
#pragma unroll
    for (int mf = 0; mf < 2; ++mf) {
#pragma unroll
        for (int r = 0; r < 16; ++r) {
            float s = exp2f(acc[mf][0][r] - LSE_SHIFT) + exp2f(acc[mf][1][r] - LSE_SHIFT);
#pragma unroll
            for (int off = 1; off < 32; off <<= 1) s += __shfl_xor(s, off);
            if (l31 == r) {
                const int rloc = wm * 64 + mf * 32 + (r & 3) + 8 * (r >> 2) + 4 * h;
                sbuf[rloc][wn] = s;
            }
        }
    }
    __syncthreads();
    if (tid < BM) {
        const float s = sbuf[tid][0] + sbuf[tid][1];
        psum[(size_t)(rt * BM + tid) * NCC + cc] = s;
    }
}

// ---------- 3. per-row partial combine (diag precomputed in gram) ----------
__global__ __launch_bounds__(256) void rowfinal_kernel(const float* __restrict__ psum,
                                                       const float* __restrict__ diag,
                                                       float* __restrict__ contrib) {
    const int i = blockIdx.x * 256 + threadIdx.x;   // row 0..4095
    float4 ps[8];
#pragma unroll
    for (int q = 0; q < 8; ++q)
        ps[q] = reinterpret_cast<const float4*>(psum + (size_t)i * NCC)[q];
    float s = 0.f;
#pragma unroll
    for (int q = 0; q < 8; ++q) s += (ps[q].x + ps[q].y) + (ps[q].z + ps[q].w);
    contrib[i] = LSE_SHIFT + log2f(s) - diag[i];   // exp2-domain LSE minus u_ii
}

// ---------- 4. deterministic final reduce ----------
__global__ __launch_bounds__(256) void final_kernel(const float* __restrict__ contrib,
                                                    float* __restrict__ out) {
    const int tid = threadIdx.x;
    float s = 0.f;
    for (int j = tid; j < NROWS; j += 256) s += contrib[j];
#pragma unroll
    for (int off = 32; off > 0; off >>= 1) s += __shfl_down(s, off);
    __shared__ float red[4];
    const int lane = tid & 63, wid = tid >> 6;
    if (lane == 0) red[wid] = s;
    __syncthreads();
    if (tid == 0) out[0] = (red[0] + red[1] + red[2] + red[3]) * (LN2 / (float)NROWS);
}

extern "C" void kernel_launch(void* const* d_in, const int* in_sizes, int n_in,
                              void* d_out, int out_size, void* d_ws, size_t ws_size,
                              hipStream_t stream) {
    const float* feat = (const float*)d_in[0];
    unsigned char* zn = (unsigned char*)d_ws;
    float* psum    = (float*)((char*)d_ws + 8388608);
    float* diag    = (float*)((char*)d_ws + 8912896);
    float* contrib = (float*)((char*)d_ws + 8929280);
    float* out = (float*)d_out;

    nrm_kernel<<<8192, 256, 0, stream>>>(feat, zn);
    gram_lse_kernel<<<1024, 256, 0, stream>>>(zn, psum, diag);
    rowfinal_kernel<<<16, 256, 0, stream>>>(psum, diag, contrib);
    final_kernel<<<1, 256, 0, stream>>>(contrib, out);
}

// Round 7
// 88.264 us; speedup vs baseline: 1.4506x; 1.4506x over previous
//
#include <hip/hip_runtime.h>
#include <hip/hip_bf16.h>

typedef __attribute__((ext_vector_type(4))) int   i32x4;
typedef __attribute__((ext_vector_type(8))) int   i32x8;
typedef __attribute__((ext_vector_type(16))) float f32x16;

#define D 1024
#define NROWS 4096          // B
#define SCALE_U 14.426950408889634f   // (1/T) * log2(e)
#define LN2 0.69314718055994530942f
#define LSE_SHIFT 16.0f     // |u| <= 14.43 => exp2(u-16) in [2^-30.5, 2^-1.5]: no max needed
#define NCC 32              // column chunks — one 128-col block each
#define BM 128              // block tile rows/cols
#define BKB 128             // K bytes (fp8 elems) per slab
#define NSLAB 8             // D / BKB

// ---------------- workspace layout ----------------
// zn      : 8192*1024 fp8 e4m3 (z1 rows pre-scaled by SCALE_U) @ 0        (8 MiB)
// psum    : 4096*32 f32                                        @ 8388608  (512 KiB)
// diag    : 4096 f32                                           @ 8912896  (16 KiB)
// contrib : 4096 f32                                           @ 8929280  (16 KiB)

__device__ __forceinline__ void gload16(const void* g, void* l) {
    __builtin_amdgcn_global_load_lds((const __attribute__((address_space(1))) void*)g,
                                     (__attribute__((address_space(3))) void*)l, 16, 0, 0);
}

// ---------- 1. row normalize + fp8 e4m3 cast (z1 rows pre-scaled) ----------
__global__ __launch_bounds__(256) void nrm_kernel(const float* __restrict__ feat,
                                                  unsigned char* __restrict__ zn) {
    const int row = blockIdx.x;           // 0..8191
    const int tid = threadIdx.x;          // 256, 4 floats each
    const float4 v = reinterpret_cast<const float4*>(feat + (size_t)row * D)[tid];
    float ss = v.x * v.x + v.y * v.y + v.z * v.z + v.w * v.w;
#pragma unroll
    for (int off = 32; off > 0; off >>= 1) ss += __shfl_down(ss, off);
    __shared__ float red[4];
    const int lane = tid & 63, wid = tid >> 6;
    if (lane == 0) red[wid] = ss;
    __syncthreads();
    const float tot = red[0] + red[1] + red[2] + red[3];
    const float nrm = fmaxf(sqrtf(tot), 1e-8f);
    const float sc = ((row < NROWS) ? SCALE_U : 1.0f) / nrm;
    int p = __builtin_amdgcn_cvt_pk_fp8_f32(v.x * sc, v.y * sc, 0, false);
    p     = __builtin_amdgcn_cvt_pk_fp8_f32(v.z * sc, v.w * sc, p, true);
    reinterpret_cast<int*>(zn)[(size_t)row * (D / 4) + tid] = p;
}

// ---------- 2. Gram (u = logits*log2e), MX-fp8 32x32x64, + fused LSE sums ----------
// R5-proven 2-phase structure, fp8 operands. launch_bounds (256,3): ~170 VGPR cap
// (m97 regime) — R6's (256,4)=128 cap spilled ~850 B/thread (222 MB scratch writes)
// and thrashed L2. Inner loop holds a0,a1 + ONE live b fragment to cut peak
// register pressure. MFMA: mfma_scale_f32_32x32x64_f8f6f4, E8M0 scale 127 (=1.0).
__global__ __launch_bounds__(256, 3) void gram_lse_kernel(const unsigned char* __restrict__ zn,
                                                          float* __restrict__ psum,
                                                          float* __restrict__ diag) {
    __shared__ __align__(16) unsigned char As[BM * BKB];   // 16 KiB
    __shared__ __align__(16) unsigned char Bs[BM * BKB];   // 16 KiB
    __shared__ float sbuf[BM][2];

    // XCD-aware swizzle: each XCD covers a 16-rowtile x 8-coltile region
    const int bid = blockIdx.x;            // 0..1023
    const int xcd = bid & 7, t = bid >> 3; // t: 0..127 within XCD
    const int rt = (xcd >> 2) * 16 + (t >> 3);   // 0..31
    const int cc = (xcd & 3) * 8 + (t & 7);      // 0..31

    const int tid = threadIdx.x;
    const int lane = tid & 63;
    const int wid  = tid >> 6;        // 0..3
    const int wm = wid >> 1, wn = wid & 1;
    const int l31 = lane & 31, h = lane >> 5;
    const int xr = l31 & 7;           // row&7 for all fragment rows (bases are mult of 8)

    const unsigned char* z1 = zn;
    const unsigned char* z2 = zn + (size_t)NROWS * D;

    // staging: 8 lanes per 128B row; source chunk pre-swizzled so
    // LDS[row][p] = global[row][p ^ (row&7)]
    const int lrow8 = lane >> 3;                       // 0..7 == row&7
    const int cs    = (lane & 7) ^ lrow8;
    const unsigned char* gA = z1 + (size_t)(rt * BM + lrow8) * D + cs * 16;
    const unsigned char* gB = z2 + (size_t)(cc * BM + lrow8) * D + cs * 16;

    // fragment LDS row bases (bytes)
    const int rA0 = (wm * 64 + l31) * BKB, rA1 = rA0 + 32 * BKB;
    const int rB0 = (wn * 64 + l31) * BKB, rB1 = rB0 + 32 * BKB;

    f32x16 acc[2][2];
#pragma unroll
    for (int i = 0; i < 2; i++)
#pragma unroll
        for (int j = 0; j < 2; j++)
#pragma unroll
            for (int r = 0; r < 16; r++) acc[i][j][r] = 0.f;

#define LDFRAG(dst, arr, rbase, ch) do {                                                   \
    const i32x4 _lo = *reinterpret_cast<const i32x4*>(&(arr)[(rbase) + (((ch)    ) ^ xr) * 16]); \
    const i32x4 _hi = *reinterpret_cast<const i32x4*>(&(arr)[(rbase) + (((ch) + 1) ^ xr) * 16]); \
    dst = __builtin_shufflevector(_lo, _hi, 0, 1, 2, 3, 4, 5, 6, 7); } while (0)

    for (int kb = 0; kb < NSLAB; ++kb) {
        __syncthreads();   // previous-iter readers done before overwrite
#pragma unroll
        for (int it = 0; it < 4; ++it) {
            const int r0 = (wid * 4 + it) * 8;         // wave-uniform row base
            gload16(gA + (size_t)r0 * D + kb * BKB, &As[r0 * BKB]);
            gload16(gB + (size_t)r0 * D + kb * BKB, &Bs[r0 * BKB]);
        }
        __syncthreads();   // vmcnt(0) drain: LDS tiles ready
#pragma unroll
        for (int kk = 0; kk < 2; ++kk) {
            const int ch = kk * 4 + h * 2;
            i32x8 a0, a1, bb;
            LDFRAG(a0, As, rA0, ch);
            LDFRAG(a1, As, rA1, ch);
            LDFRAG(bb, Bs, rB0, ch);
            acc[0][0] = __builtin_amdgcn_mfma_scale_f32_32x32x64_f8f6f4(
                a0, bb, acc[0][0], 0, 0, 0, 0x7f7f7f7f, 0, 0x7f7f7f7f);
            acc[1][0] = __builtin_amdgcn_mfma_scale_f32_32x32x64_f8f6f4(
                a1, bb, acc[1][0], 0, 0, 0, 0x7f7f7f7f, 0, 0x7f7f7f7f);
            LDFRAG(bb, Bs, rB1, ch);
            acc[0][1] = __builtin_amdgcn_mfma_scale_f32_32x32x64_f8f6f4(
                a0, bb, acc[0][1], 0, 0, 0, 0x7f7f7f7f, 0, 0x7f7f7f7f);
            acc[1][1] = __builtin_amdgcn_mfma_scale_f32_32x32x64_f8f6f4(
                a1, bb, acc[1][1], 0, 0, 0, 0x7f7f7f7f, 0, 0x7f7f7f7f);
        }
    }
#undef LDFRAG

    // ---- diagonal extraction (u_ii) on the 32 rt==cc blocks ----
    // 32x32 C/D layout: col = lane&31, row = (r&3) + 8*(r>>2) + 4*(lane>>5)
    if (rt == cc) {
#pragma unroll
        for (int mf = 0; mf < 2; ++mf)
#pragma unroll
            for (int nf = 0; nf < 2; ++nf)
#pragma unroll
                for (int r = 0; r < 16; ++r) {
                    const int rl = wm * 64 + mf * 32 + (r & 3) + 8 * (r >> 2) + 4 * h;
                    const int cl = wn * 64 + nf * 32 + l31;
                    if (rl == cl) diag[rt * BM + rl] = acc[mf][nf][r];
                }
    }

    // ---- fused LSE partial sums (fixed shift, no max): s = sum exp2(u - 16) ----
    // For each reg r: 32 cols live in the 32 lanes of this half -> butterfly-sum.
#pragma unroll
    for (int mf = 0; mf < 2; ++mf) {
#pragma unroll
        for (int r = 0; r < 16; ++r) {
            float s = exp2f(acc[mf][0][r] - LSE_SHIFT) + exp2f(acc[mf][1][r] - LSE_SHIFT);
#pragma unroll
            for (int off = 1; off < 32; off <<= 1) s += __shfl_xor(s, off);
            if (l31 == r) {
                const int rloc = wm * 64 + mf * 32 + (r & 3) + 8 * (r >> 2) + 4 * h;
                sbuf[rloc][wn] = s;
            }
        }
    }
    __syncthreads();
    if (tid < BM) {
        const float s = sbuf[tid][0] + sbuf[tid][1];
        psum[(size_t)(rt * BM + tid) * NCC + cc] = s;
    }
}

// ---------- 3. per-row partial combine (diag precomputed in gram) ----------
__global__ __launch_bounds__(256) void rowfinal_kernel(const float* __restrict__ psum,
                                                       const float* __restrict__ diag,
                                                       float* __restrict__ contrib) {
    const int i = blockIdx.x * 256 + threadIdx.x;   // row 0..4095
    float4 ps[8];
#pragma unroll
    for (int q = 0; q < 8; ++q)
        ps[q] = reinterpret_cast<const float4*>(psum + (size_t)i * NCC)[q];
    float s = 0.f;
#pragma unroll
    for (int q = 0; q < 8; ++q) s += (ps[q].x + ps[q].y) + (ps[q].z + ps[q].w);
    contrib[i] = LSE_SHIFT + log2f(s) - diag[i];   // exp2-domain LSE minus u_ii
}

// ---------- 4. deterministic final reduce ----------
__global__ __launch_bounds__(256) void final_kernel(const float* __restrict__ contrib,
                                                    float* __restrict__ out) {
    const int tid = threadIdx.x;
    float s = 0.f;
    for (int j = tid; j < NROWS; j += 256) s += contrib[j];
#pragma unroll
    for (int off = 32; off > 0; off >>= 1) s += __shfl_down(s, off);
    __shared__ float red[4];
    const int lane = tid & 63, wid = tid >> 6;
    if (lane == 0) red[wid] = s;
    __syncthreads();
    if (tid == 0) out[0] = (red[0] + red[1] + red[2] + red[3]) * (LN2 / (float)NROWS);
}

extern "C" void kernel_launch(void* const* d_in, const int* in_sizes, int n_in,
                              void* d_out, int out_size, void* d_ws, size_t ws_size,
                              hipStream_t stream) {
    const float* feat = (const float*)d_in[0];
    unsigned char* zn = (unsigned char*)d_ws;
    float* psum    = (float*)((char*)d_ws + 8388608);
    float* diag    = (float*)((char*)d_ws + 8912896);
    float* contrib = (float*)((char*)d_ws + 8929280);
    float* out = (float*)d_out;

    nrm_kernel<<<8192, 256, 0, stream>>>(feat, zn);
    gram_lse_kernel<<<1024, 256, 0, stream>>>(zn, psum, diag);
    rowfinal_kernel<<<16, 256, 0, stream>>>(psum, diag, contrib);
    final_kernel<<<1, 256, 0, stream>>>(contrib, out);
}